// Round 1
// baseline (390.059 us; speedup 1.0000x reference)
//
#include <hip/hip_runtime.h>
#include <hip/hip_bf16.h>

typedef __attribute__((ext_vector_type(8))) __bf16 bf16x8;
typedef __attribute__((ext_vector_type(4))) float f32x4;

// Problem constants: B=32, L=64, C=128, D=512, O=256, L2=4096
// Rows (b,i) flattened: 2048 rows total.

// ---------------- K1: u = x@w1[:128] + b1 ; v = x@w1[128:] --------------
__global__ __launch_bounds__(256) void k_uv(const float* __restrict__ x,
                                            const float* __restrict__ w1,
                                            const float* __restrict__ b1,
                                            float* __restrict__ u,
                                            float* __restrict__ v) {
  __shared__ float xs[8 * 128];
  int t = threadIdx.x;
  int r0 = blockIdx.x * 8;  // 256 blocks * 8 rows = 2048 rows
  // load 8 x-rows (x row stride 128 floats; flat row == b*64+i)
  ((float4*)xs)[t] = ((const float4*)(x + (size_t)r0 * 128))[t];
  __syncthreads();
  int d1 = t, d2 = t + 256;
  float au0[8], au1[8], av0[8], av1[8];
  float bb1 = b1[d1], bb2 = b1[d2];
#pragma unroll
  for (int r = 0; r < 8; ++r) { au0[r] = bb1; au1[r] = bb2; av0[r] = 0.f; av1[r] = 0.f; }
#pragma unroll 4
  for (int c = 0; c < 128; ++c) {
    float wu1 = w1[c * 512 + d1];
    float wu2 = w1[c * 512 + d2];
    float wv1 = w1[(c + 128) * 512 + d1];
    float wv2 = w1[(c + 128) * 512 + d2];
#pragma unroll
    for (int r = 0; r < 8; ++r) {
      float xv = xs[r * 128 + c];
      au0[r] = fmaf(xv, wu1, au0[r]);
      au1[r] = fmaf(xv, wu2, au1[r]);
      av0[r] = fmaf(xv, wv1, av0[r]);
      av1[r] = fmaf(xv, wv2, av1[r]);
    }
  }
#pragma unroll
  for (int r = 0; r < 8; ++r) {
    u[(size_t)(r0 + r) * 512 + d1] = au0[r];
    u[(size_t)(r0 + r) * 512 + d2] = au1[r];
    v[(size_t)(r0 + r) * 512 + d1] = av0[r];
    v[(size_t)(r0 + r) * 512 + d2] = av1[r];
  }
}

// ---------------- K2: w2t[n][k] = bf16(w2[k][n])  (256x512) -------------
__global__ __launch_bounds__(256) void k_w2t(const float* __restrict__ w2,
                                             __bf16* __restrict__ w2t) {
  int n = blockIdx.x;
  int t = threadIdx.x;
  w2t[(size_t)n * 512 + t]       = (__bf16)w2[(size_t)t * 256 + n];
  w2t[(size_t)n * 512 + t + 256] = (__bf16)w2[(size_t)(t + 256) * 256 + n];
}

// ---------------- K3: pwt[o][l] = pool_w[l][o]  (256x4096) --------------
__global__ __launch_bounds__(256) void k_pwt(const float* __restrict__ pw,
                                             float* __restrict__ pwt) {
  int o = blockIdx.x;
  int t = threadIdx.x;
#pragma unroll
  for (int it = 0; it < 16; ++it) {
    int l = it * 256 + t;
    pwt[(size_t)o * 4096 + l] = pw[(size_t)l * 256 + o];
  }
}

// ------- K4: fused h=relu(u_i+v_j) -> bf16 MFMA @ w2t -> y^T store ------
// block = (b,i); computes y[b, i*64 + j, n] for j=0..63, n=0..255
// stored transposed: yt[((b*256+n))*4096 + i*64 + j]
__global__ __launch_bounds__(256, 1) void k_gemm(const float* __restrict__ u,
                                                 const float* __restrict__ v,
                                                 const __bf16* __restrict__ w2t,
                                                 const float* __restrict__ b2,
                                                 float* __restrict__ yt) {
  __shared__ __bf16 hl[64 * 512];  // 64 KiB, XOR-swizzled rows
  __shared__ float ul[512];
  int t = threadIdx.x;
  int b = blockIdx.x >> 6, i = blockIdx.x & 63;
  if (t < 128) ((float4*)ul)[t] = ((const float4*)(u + (size_t)(b * 64 + i) * 512))[t];
  __syncthreads();
  // build h tile: thread -> row j = t>>2, d-quarter q = t&3 (128 d's each)
  {
    int j = t >> 2, q = t & 3;
    const float* vrow = v + (size_t)(b * 64 + j) * 512;
#pragma unroll 4
    for (int it = 0; it < 16; ++it) {
      int d0 = q * 128 + it * 8;
      float4 va = *(const float4*)(vrow + d0);
      float4 vb = *(const float4*)(vrow + d0 + 4);
      bf16x8 hv;
      hv[0] = (__bf16)fmaxf(ul[d0 + 0] + va.x, 0.f);
      hv[1] = (__bf16)fmaxf(ul[d0 + 1] + va.y, 0.f);
      hv[2] = (__bf16)fmaxf(ul[d0 + 2] + va.z, 0.f);
      hv[3] = (__bf16)fmaxf(ul[d0 + 3] + va.w, 0.f);
      hv[4] = (__bf16)fmaxf(ul[d0 + 4] + vb.x, 0.f);
      hv[5] = (__bf16)fmaxf(ul[d0 + 5] + vb.y, 0.f);
      hv[6] = (__bf16)fmaxf(ul[d0 + 6] + vb.z, 0.f);
      hv[7] = (__bf16)fmaxf(ul[d0 + 7] + vb.w, 0.f);
      int e = j * 512 + d0;
      *(bf16x8*)(hl + (e ^ ((j & 7) << 3))) = hv;  // byte-XOR ((j&7)<<4)
    }
  }
  __syncthreads();
  // MFMA: 4 waves, wave w owns n in [64w, 64w+64)
  int w = t >> 6, l = t & 63;
  int lr = l & 15, lg = l >> 4;
  f32x4 acc[4][4];
  const __bf16* bptr[4];
#pragma unroll
  for (int ni = 0; ni < 4; ++ni) {
    int col = w * 64 + ni * 16 + lr;
    bptr[ni] = w2t + (size_t)col * 512 + lg * 8;
    float bias = b2[col];
    f32x4 cinit = {bias, bias, bias, bias};
#pragma unroll
    for (int mi = 0; mi < 4; ++mi) acc[mi][ni] = cinit;
  }
#pragma unroll 4
  for (int kk = 0; kk < 16; ++kk) {
    int kb = kk * 32 + lg * 8;
    bf16x8 af[4];
#pragma unroll
    for (int mi = 0; mi < 4; ++mi) {
      int row = mi * 16 + lr;
      int e = row * 512 + kb;
      af[mi] = *(const bf16x8*)(hl + (e ^ ((row & 7) << 3)));
    }
    bf16x8 bfv[4];
#pragma unroll
    for (int ni = 0; ni < 4; ++ni) bfv[ni] = *(const bf16x8*)(bptr[ni] + kk * 32);
#pragma unroll
    for (int mi = 0; mi < 4; ++mi)
#pragma unroll
      for (int ni = 0; ni < 4; ++ni)
        acc[mi][ni] = __builtin_amdgcn_mfma_f32_16x16x32_bf16(af[mi], bfv[ni], acc[mi][ni], 0, 0, 0);
  }
  // epilogue: C/D layout col=lane&15, row=(lane>>4)*4+reg  -> float4 to yt
#pragma unroll
  for (int ni = 0; ni < 4; ++ni) {
    int col = w * 64 + ni * 16 + lr;
    float* colbase = yt + (size_t)(b * 256 + col) * 4096 + i * 64;
#pragma unroll
    for (int mi = 0; mi < 4; ++mi) {
      *(f32x4*)(colbase + mi * 16 + lg * 4) = acc[mi][ni];
    }
  }
}

// -------- K5: per-(b,o) column: bitonic sort 4096 + weighted sum --------
__global__ __launch_bounds__(256) void k_sortpool(const float* __restrict__ yt,
                                                  const float* __restrict__ pwt,
                                                  float* __restrict__ out) {
  __shared__ float sl[4096];
  int t = threadIdx.x;
  int b = blockIdx.x >> 8, o = blockIdx.x & 255;
  const float* col = yt + (size_t)(b * 256 + o) * 4096;
  float a[16];
  {
    const float4* c4 = (const float4*)(col + t * 16);
    float4 r0 = c4[0], r1 = c4[1], r2 = c4[2], r3 = c4[3];
    a[0] = r0.x; a[1] = r0.y; a[2] = r0.z; a[3] = r0.w;
    a[4] = r1.x; a[5] = r1.y; a[6] = r1.z; a[7] = r1.w;
    a[8] = r2.x; a[9] = r2.y; a[10] = r2.z; a[11] = r2.w;
    a[12] = r3.x; a[13] = r3.y; a[14] = r3.z; a[15] = r3.w;
  }
#define CE(X, Y, ASC)                                   \
  {                                                     \
    float lo_ = fminf(a[(X)], a[(Y)]);                  \
    float hi_ = fmaxf(a[(X)], a[(Y)]);                  \
    bool as_ = (ASC);                                   \
    a[(X)] = as_ ? lo_ : hi_;                           \
    a[(Y)] = as_ ? hi_ : lo_;                           \
  }
  // local stages k=2,4,8 (direction from element bits; i = 16t+e)
#pragma unroll
  for (int e = 0; e < 16; ++e) if ((e & 1) == 0) CE(e, e ^ 1, ((e & 2) == 0));
#pragma unroll
  for (int e = 0; e < 16; ++e) if ((e & 2) == 0) CE(e, e ^ 2, ((e & 4) == 0));
#pragma unroll
  for (int e = 0; e < 16; ++e) if ((e & 1) == 0) CE(e, e ^ 1, ((e & 4) == 0));
#pragma unroll
  for (int e = 0; e < 16; ++e) if ((e & 4) == 0) CE(e, e ^ 4, ((e & 8) == 0));
#pragma unroll
  for (int e = 0; e < 16; ++e) if ((e & 2) == 0) CE(e, e ^ 2, ((e & 8) == 0));
#pragma unroll
  for (int e = 0; e < 16; ++e) if ((e & 1) == 0) CE(e, e ^ 1, ((e & 8) == 0));
  // stage k=16: direction uniform per thread
  {
    bool asc16 = ((t & 1) == 0);
#pragma unroll
    for (int e = 0; e < 16; ++e) if ((e & 8) == 0) CE(e, e ^ 8, asc16);
#pragma unroll
    for (int e = 0; e < 16; ++e) if ((e & 4) == 0) CE(e, e ^ 4, asc16);
#pragma unroll
    for (int e = 0; e < 16; ++e) if ((e & 2) == 0) CE(e, e ^ 2, asc16);
#pragma unroll
    for (int e = 0; e < 16; ++e) if ((e & 1) == 0) CE(e, e ^ 1, asc16);
  }
#define INTRA(ASC)                                                          \
  {                                                                         \
    _Pragma("unroll") for (int e = 0; e < 16; ++e) if ((e & 8) == 0)        \
        CE(e, e ^ 8, (ASC));                                                \
    _Pragma("unroll") for (int e = 0; e < 16; ++e) if ((e & 4) == 0)        \
        CE(e, e ^ 4, (ASC));                                                \
    _Pragma("unroll") for (int e = 0; e < 16; ++e) if ((e & 2) == 0)        \
        CE(e, e ^ 2, (ASC));                                                \
    _Pragma("unroll") for (int e = 0; e < 16; ++e) if ((e & 1) == 0)        \
        CE(e, e ^ 1, (ASC));                                                \
  }
  // stages k=32..4096: cross-thread passes (j>=16) via LDS, then intra
  for (int k = 32; k <= 4096; k <<= 1) {
    bool asc = ((t & (k >> 4)) == 0);
    for (int j = k >> 1; j >= 16; j >>= 1) {
      int jt = j >> 4;
      bool lower = ((t & jt) == 0);
      bool keepmin = (asc == lower);
      __syncthreads();
#pragma unroll
      for (int e = 0; e < 16; ++e) sl[e * 256 + t] = a[e];
      __syncthreads();
      int pt = t ^ jt;
#pragma unroll
      for (int e = 0; e < 16; ++e) {
        float p = sl[e * 256 + pt];
        a[e] = keepmin ? fminf(a[e], p) : fmaxf(a[e], p);
      }
    }
    INTRA(asc);
  }
  // rank-weighted sum: rank of a[e] is 16t+e
  const float* pwrow = pwt + (size_t)o * 4096 + t * 16;
  float s = 0.f;
#pragma unroll
  for (int e = 0; e < 16; ++e) s = fmaf(a[e], pwrow[e], s);
#pragma unroll
  for (int off = 32; off > 0; off >>= 1) s += __shfl_down(s, off);
  __syncthreads();
  if ((t & 63) == 0) sl[t >> 6] = s;
  __syncthreads();
  if (t == 0) out[b * 256 + o] = sl[0] + sl[1] + sl[2] + sl[3];
}

extern "C" void kernel_launch(void* const* d_in, const int* in_sizes, int n_in,
                              void* d_out, int out_size, void* d_ws, size_t ws_size,
                              hipStream_t stream) {
  const float* x  = (const float*)d_in[0];
  const float* w1 = (const float*)d_in[1];
  const float* b1 = (const float*)d_in[2];
  const float* w2 = (const float*)d_in[3];
  const float* b2 = (const float*)d_in[4];
  const float* pw = (const float*)d_in[5];
  char* ws = (char*)d_ws;
  float*  u   = (float*)ws;                                        // 4 MiB
  float*  v   = (float*)(ws + (4u << 20));                         // 4 MiB
  __bf16* w2t = (__bf16*)(ws + (8u << 20));                        // 256 KiB
  float*  pwt = (float*)(ws + (8u << 20) + (256u << 10));          // 4 MiB
  float*  yt  = (float*)(ws + (12u << 20) + (256u << 10));         // 128 MiB
  float* out = (float*)d_out;

  k_uv<<<dim3(256), dim3(256), 0, stream>>>(x, w1, b1, u, v);
  k_w2t<<<dim3(256), dim3(256), 0, stream>>>(w2, w2t);
  k_pwt<<<dim3(256), dim3(256), 0, stream>>>(pw, pwt);
  k_gemm<<<dim3(2048), dim3(256), 0, stream>>>(u, v, w2t, b2, yt);
  k_sortpool<<<dim3(8192), dim3(256), 0, stream>>>(yt, pwt, out);
}

// Round 3
// 237.730 us; speedup vs baseline: 1.6408x; 1.6408x over previous
//
#include <hip/hip_runtime.h>
#include <hip/hip_bf16.h>
#include <hip/hip_fp16.h>

typedef __attribute__((ext_vector_type(8))) __bf16 bf16x8;
typedef __attribute__((ext_vector_type(4))) float f32x4;
typedef _Float16 h2 __attribute__((ext_vector_type(2)));

static __device__ __forceinline__ h2 h2min(h2 x, h2 y) { return __builtin_elementwise_min(x, y); }
static __device__ __forceinline__ h2 h2max(h2 x, h2 y) { return __builtin_elementwise_max(x, y); }
static __device__ __forceinline__ int h2i(h2 x) { return __builtin_bit_cast(int, x); }
static __device__ __forceinline__ h2 ih2(int x) { return __builtin_bit_cast(h2, x); }
static __device__ __forceinline__ unsigned pkrtz(float lo, float hi) {
  return __builtin_bit_cast(unsigned, __builtin_amdgcn_cvt_pkrtz(lo, hi));
}

// Problem constants: B=32, L=64, C=128, D=512, O=256, L2=4096

// ---------------- K1: u = x@w1[:128] + b1 ; v = x@w1[128:] --------------
__global__ __launch_bounds__(256) void k_uv(const float* __restrict__ x,
                                            const float* __restrict__ w1,
                                            const float* __restrict__ b1,
                                            float* __restrict__ u,
                                            float* __restrict__ v) {
  __shared__ float xs[8 * 128];
  int t = threadIdx.x;
  int r0 = blockIdx.x * 8;
  ((float4*)xs)[t] = ((const float4*)(x + (size_t)r0 * 128))[t];
  __syncthreads();
  int d1 = t, d2 = t + 256;
  float au0[8], au1[8], av0[8], av1[8];
  float bb1 = b1[d1], bb2 = b1[d2];
#pragma unroll
  for (int r = 0; r < 8; ++r) { au0[r] = bb1; au1[r] = bb2; av0[r] = 0.f; av1[r] = 0.f; }
#pragma unroll 4
  for (int c = 0; c < 128; ++c) {
    float wu1 = w1[c * 512 + d1];
    float wu2 = w1[c * 512 + d2];
    float wv1 = w1[(c + 128) * 512 + d1];
    float wv2 = w1[(c + 128) * 512 + d2];
#pragma unroll
    for (int r = 0; r < 8; ++r) {
      float xv = xs[r * 128 + c];
      au0[r] = fmaf(xv, wu1, au0[r]);
      au1[r] = fmaf(xv, wu2, au1[r]);
      av0[r] = fmaf(xv, wv1, av0[r]);
      av1[r] = fmaf(xv, wv2, av1[r]);
    }
  }
#pragma unroll
  for (int r = 0; r < 8; ++r) {
    u[(size_t)(r0 + r) * 512 + d1] = au0[r];
    u[(size_t)(r0 + r) * 512 + d2] = au1[r];
    v[(size_t)(r0 + r) * 512 + d1] = av0[r];
    v[(size_t)(r0 + r) * 512 + d2] = av1[r];
  }
}

// ---------------- K2: w2t[n][k] = bf16(w2[k][n])  (256x512) -------------
__global__ __launch_bounds__(256) void k_w2t(const float* __restrict__ w2,
                                             __bf16* __restrict__ w2t) {
  int n = blockIdx.x;
  int t = threadIdx.x;
  w2t[(size_t)n * 512 + t]       = (__bf16)w2[(size_t)t * 256 + n];
  w2t[(size_t)n * 512 + t + 256] = (__bf16)w2[(size_t)(t + 256) * 256 + n];
}

// ---------------- K3: pwt[o][l] = pool_w[l][o]  (256x4096) --------------
__global__ __launch_bounds__(256) void k_pwt(const float* __restrict__ pw,
                                             float* __restrict__ pwt) {
  int o = blockIdx.x;
  int t = threadIdx.x;
#pragma unroll
  for (int it = 0; it < 16; ++it) {
    int l = it * 256 + t;
    pwt[(size_t)o * 4096 + l] = pw[(size_t)l * 256 + o];
  }
}

// ------- K4: fused h=relu(u_i+v_j) -> bf16 MFMA @ w2t -> f16 y^T --------
__global__ __launch_bounds__(256, 1) void k_gemm(const float* __restrict__ u,
                                                 const float* __restrict__ v,
                                                 const __bf16* __restrict__ w2t,
                                                 const float* __restrict__ b2,
                                                 unsigned short* __restrict__ yt) {
  __shared__ __bf16 hl[64 * 512];
  __shared__ float ul[512];
  int t = threadIdx.x;
  int b = blockIdx.x >> 6, i = blockIdx.x & 63;
  if (t < 128) ((float4*)ul)[t] = ((const float4*)(u + (size_t)(b * 64 + i) * 512))[t];
  __syncthreads();
  {
    int j = t >> 2, q = t & 3;
    const float* vrow = v + (size_t)(b * 64 + j) * 512;
#pragma unroll 4
    for (int it = 0; it < 16; ++it) {
      int d0 = q * 128 + it * 8;
      float4 va = *(const float4*)(vrow + d0);
      float4 vb = *(const float4*)(vrow + d0 + 4);
      bf16x8 hv;
      hv[0] = (__bf16)fmaxf(ul[d0 + 0] + va.x, 0.f);
      hv[1] = (__bf16)fmaxf(ul[d0 + 1] + va.y, 0.f);
      hv[2] = (__bf16)fmaxf(ul[d0 + 2] + va.z, 0.f);
      hv[3] = (__bf16)fmaxf(ul[d0 + 3] + va.w, 0.f);
      hv[4] = (__bf16)fmaxf(ul[d0 + 4] + vb.x, 0.f);
      hv[5] = (__bf16)fmaxf(ul[d0 + 5] + vb.y, 0.f);
      hv[6] = (__bf16)fmaxf(ul[d0 + 6] + vb.z, 0.f);
      hv[7] = (__bf16)fmaxf(ul[d0 + 7] + vb.w, 0.f);
      int e = j * 512 + d0;
      *(bf16x8*)(hl + (e ^ ((j & 7) << 3))) = hv;
    }
  }
  __syncthreads();
  int w = t >> 6, l = t & 63;
  int lr = l & 15, lg = l >> 4;
  f32x4 acc[4][4];
  const __bf16* bptr[4];
#pragma unroll
  for (int ni = 0; ni < 4; ++ni) {
    int col = w * 64 + ni * 16 + lr;
    bptr[ni] = w2t + (size_t)col * 512 + lg * 8;
    float bias = b2[col];
    f32x4 cinit = {bias, bias, bias, bias};
#pragma unroll
    for (int mi = 0; mi < 4; ++mi) acc[mi][ni] = cinit;
  }
#pragma unroll 4
  for (int kk = 0; kk < 16; ++kk) {
    int kb = kk * 32 + lg * 8;
    bf16x8 af[4];
#pragma unroll
    for (int mi = 0; mi < 4; ++mi) {
      int row = mi * 16 + lr;
      int e = row * 512 + kb;
      af[mi] = *(const bf16x8*)(hl + (e ^ ((row & 7) << 3)));
    }
    bf16x8 bfv[4];
#pragma unroll
    for (int ni = 0; ni < 4; ++ni) bfv[ni] = *(const bf16x8*)(bptr[ni] + kk * 32);
#pragma unroll
    for (int mi = 0; mi < 4; ++mi)
#pragma unroll
      for (int ni = 0; ni < 4; ++ni)
        acc[mi][ni] = __builtin_amdgcn_mfma_f32_16x16x32_bf16(af[mi], bfv[ni], acc[mi][ni], 0, 0, 0);
  }
  // epilogue: col=lane&15, row=(lane>>4)*4+reg -> f16 pack -> 8B store
#pragma unroll
  for (int ni = 0; ni < 4; ++ni) {
    int col = w * 64 + ni * 16 + lr;
    unsigned short* colbase = yt + (size_t)(b * 256 + col) * 4096 + (size_t)i * 64;
#pragma unroll
    for (int mi = 0; mi < 4; ++mi) {
      f32x4 vv = acc[mi][ni];
      uint2 st;
      st.x = pkrtz(vv[0], vv[1]);
      st.y = pkrtz(vv[2], vv[3]);
      *(uint2*)(colbase + mi * 16 + lg * 4) = st;
    }
  }
}

// -------- K5: packed-f16 monotone bitonic sort (2 cols/block) -----------
// intra-register pass: pairs (e, e^M), min at low index, compile-time
template <int M, int HB>
static __device__ __forceinline__ void intra(h2* a) {
#pragma unroll
  for (int e = 0; e < 16; ++e)
    if ((e & HB) == 0) {
      int f = e ^ M;
      h2 lo = h2min(a[e], a[f]);
      h2 hi = h2max(a[e], a[f]);
      a[e] = lo;
      a[f] = hi;
    }
}

// cross-lane pass within wave via ds_bpermute (partner lane = l ^ tm)
template <bool FLIP>
static __device__ __forceinline__ void xw(h2* a, int tm, bool km, int l) {
  int paddr = (l ^ tm) << 2;
  h2 r[16];
#pragma unroll
  for (int e = 0; e < 16; ++e)
    r[e] = ih2(__builtin_amdgcn_ds_bpermute(paddr, h2i(a[FLIP ? (e ^ 15) : e])));
#pragma unroll
  for (int e = 0; e < 16; ++e) a[e] = km ? h2min(a[e], r[e]) : h2max(a[e], r[e]);
}

// cross-wave pass via LDS (partner thread = t ^ tm, tm >= 64)
template <bool FLIP>
static __device__ __forceinline__ void xl(h2* a, int tm, bool km, int t, h2* sl) {
  __syncthreads();
#pragma unroll
  for (int e = 0; e < 16; ++e) sl[e * 256 + t] = a[e];
  __syncthreads();
  int pt = t ^ tm;
  h2 r[16];
#pragma unroll
  for (int e = 0; e < 16; ++e) r[e] = sl[(FLIP ? (e ^ 15) : e) * 256 + pt];
#pragma unroll
  for (int e = 0; e < 16; ++e) a[e] = km ? h2min(a[e], r[e]) : h2max(a[e], r[e]);
}

__global__ __launch_bounds__(256) void k_sortpool(const unsigned short* __restrict__ yt,
                                                  const float* __restrict__ pwt,
                                                  float* __restrict__ out) {
  __shared__ h2 sl[4096];
  __shared__ float red[8];
  int t = threadIdx.x;
  int l = t & 63;
  int b = blockIdx.x >> 7, p = blockIdx.x & 127;
  int o0 = p * 2, o1 = p * 2 + 1;
  const uint4* c0 = (const uint4*)(yt + (size_t)(b * 256 + o0) * 4096 + t * 16);
  const uint4* c1 = (const uint4*)(yt + (size_t)(b * 256 + o1) * 4096 + t * 16);
  uint4 A0 = c0[0], A1 = c0[1], B0 = c1[0], B1 = c1[1];
  unsigned cw0[8] = {A0.x, A0.y, A0.z, A0.w, A1.x, A1.y, A1.z, A1.w};
  unsigned cw1[8] = {B0.x, B0.y, B0.z, B0.w, B1.x, B1.y, B1.z, B1.w};
  h2 a[16];
#pragma unroll
  for (int q = 0; q < 8; ++q) {
    a[2 * q]     = ih2((int)((cw0[q] & 0xffffu) | (cw1[q] << 16)));
    a[2 * q + 1] = ih2((int)((cw0[q] >> 16) | (cw1[q] & 0xffff0000u)));
  }
  // intra stages k=1..8 (all compile-time min/max)
  intra<1, 1>(a);
  intra<3, 2>(a); intra<1, 1>(a);
  intra<7, 4>(a); intra<2, 2>(a); intra<1, 1>(a);
  intra<15, 8>(a); intra<4, 4>(a); intra<2, 2>(a); intra<1, 1>(a);
#define INTRA4 intra<8, 8>(a); intra<4, 4>(a); intra<2, 2>(a); intra<1, 1>(a)
  // k=16
  xw<true>(a, 1, !(t & 1), l); INTRA4;
  // k=32
  xw<true>(a, 3, !(t & 2), l); xw<false>(a, 1, !(t & 1), l); INTRA4;
  // k=64
  xw<true>(a, 7, !(t & 4), l); xw<false>(a, 2, !(t & 2), l); xw<false>(a, 1, !(t & 1), l); INTRA4;
  // k=128
  xw<true>(a, 15, !(t & 8), l); xw<false>(a, 4, !(t & 4), l); xw<false>(a, 2, !(t & 2), l);
  xw<false>(a, 1, !(t & 1), l); INTRA4;
  // k=256
  xw<true>(a, 31, !(t & 16), l); xw<false>(a, 8, !(t & 8), l); xw<false>(a, 4, !(t & 4), l);
  xw<false>(a, 2, !(t & 2), l); xw<false>(a, 1, !(t & 1), l); INTRA4;
  // k=512
  xw<true>(a, 63, !(t & 32), l); xw<false>(a, 16, !(t & 16), l); xw<false>(a, 8, !(t & 8), l);
  xw<false>(a, 4, !(t & 4), l); xw<false>(a, 2, !(t & 2), l); xw<false>(a, 1, !(t & 1), l); INTRA4;
  // k=1024
  xl<true>(a, 127, !(t & 64), t, sl);
  xw<false>(a, 32, !(t & 32), l); xw<false>(a, 16, !(t & 16), l); xw<false>(a, 8, !(t & 8), l);
  xw<false>(a, 4, !(t & 4), l); xw<false>(a, 2, !(t & 2), l); xw<false>(a, 1, !(t & 1), l); INTRA4;
  // k=2048
  xl<true>(a, 255, !(t & 128), t, sl);
  xl<false>(a, 64, !(t & 64), t, sl);
  xw<false>(a, 32, !(t & 32), l); xw<false>(a, 16, !(t & 16), l); xw<false>(a, 8, !(t & 8), l);
  xw<false>(a, 4, !(t & 4), l); xw<false>(a, 2, !(t & 2), l); xw<false>(a, 1, !(t & 1), l); INTRA4;
#undef INTRA4
  // rank-weighted sum: rank of a[e] is 16t+e; lo half -> o0, hi half -> o1
  const float* pw0 = pwt + (size_t)o0 * 4096 + t * 16;
  const float* pw1 = pwt + (size_t)o1 * 4096 + t * 16;
  float s0 = 0.f, s1 = 0.f;
#pragma unroll
  for (int e = 0; e < 16; ++e) {
    s0 = fmaf((float)a[e][0], pw0[e], s0);
    s1 = fmaf((float)a[e][1], pw1[e], s1);
  }
#pragma unroll
  for (int off = 32; off > 0; off >>= 1) {
    s0 += __shfl_xor(s0, off);
    s1 += __shfl_xor(s1, off);
  }
  int wv = t >> 6;
  if (l == 0) { red[wv * 2] = s0; red[wv * 2 + 1] = s1; }
  __syncthreads();
  if (t == 0) out[b * 256 + o0] = red[0] + red[2] + red[4] + red[6];
  if (t == 1) out[b * 256 + o1] = red[1] + red[3] + red[5] + red[7];
}

extern "C" void kernel_launch(void* const* d_in, const int* in_sizes, int n_in,
                              void* d_out, int out_size, void* d_ws, size_t ws_size,
                              hipStream_t stream) {
  const float* x  = (const float*)d_in[0];
  const float* w1 = (const float*)d_in[1];
  const float* b1 = (const float*)d_in[2];
  const float* w2 = (const float*)d_in[3];
  const float* b2 = (const float*)d_in[4];
  const float* pw = (const float*)d_in[5];
  char* ws = (char*)d_ws;
  float*  u   = (float*)ws;                                        // 4 MiB
  float*  v   = (float*)(ws + (4u << 20));                         // 4 MiB
  __bf16* w2t = (__bf16*)(ws + (8u << 20));                        // 256 KiB
  float*  pwt = (float*)(ws + (8u << 20) + (256u << 10));          // 4 MiB
  unsigned short* yt = (unsigned short*)(ws + (12u << 20) + (256u << 10));  // 64 MiB f16
  float* out = (float*)d_out;

  k_uv<<<dim3(256), dim3(256), 0, stream>>>(x, w1, b1, u, v);
  k_w2t<<<dim3(256), dim3(256), 0, stream>>>(w2, w2t);
  k_pwt<<<dim3(256), dim3(256), 0, stream>>>(pw, pwt);
  k_gemm<<<dim3(2048), dim3(256), 0, stream>>>(u, v, w2t, b2, yt);
  k_sortpool<<<dim3(4096), dim3(256), 0, stream>>>(yt, pwt, out);
}

// Round 4
// 230.444 us; speedup vs baseline: 1.6926x; 1.0316x over previous
//
#include <hip/hip_runtime.h>
#include <hip/hip_bf16.h>
#include <hip/hip_fp16.h>

typedef __attribute__((ext_vector_type(8))) __bf16 bf16x8;
typedef __attribute__((ext_vector_type(4))) float f32x4;
typedef _Float16 h2 __attribute__((ext_vector_type(2)));

static __device__ __forceinline__ h2 ih2(int x) { return __builtin_bit_cast(h2, x); }
static __device__ __forceinline__ unsigned pkrtz(float lo, float hi) {
  return __builtin_bit_cast(unsigned, __builtin_amdgcn_cvt_pkrtz(lo, hi));
}
// forced packed f16 min/max (2 independent sort columns per 32-bit reg)
static __device__ __forceinline__ int pkmin(int x, int y) {
  int d; asm("v_pk_min_f16 %0, %1, %2" : "=v"(d) : "v"(x), "v"(y)); return d;
}
static __device__ __forceinline__ int pkmax(int x, int y) {
  int d; asm("v_pk_max_f16 %0, %1, %2" : "=v"(d) : "v"(x), "v"(y)); return d;
}

// Problem constants: B=32, L=64, C=128, D=512, O=256, L2=4096

// ---------------- K1: u = x@w1[:128] + b1 ; v = x@w1[128:] --------------
__global__ __launch_bounds__(256) void k_uv(const float* __restrict__ x,
                                            const float* __restrict__ w1,
                                            const float* __restrict__ b1,
                                            float* __restrict__ u,
                                            float* __restrict__ v) {
  __shared__ float xs[8 * 128];
  int t = threadIdx.x;
  int r0 = blockIdx.x * 8;
  ((float4*)xs)[t] = ((const float4*)(x + (size_t)r0 * 128))[t];
  __syncthreads();
  int d1 = t, d2 = t + 256;
  float au0[8], au1[8], av0[8], av1[8];
  float bb1 = b1[d1], bb2 = b1[d2];
#pragma unroll
  for (int r = 0; r < 8; ++r) { au0[r] = bb1; au1[r] = bb2; av0[r] = 0.f; av1[r] = 0.f; }
#pragma unroll 4
  for (int c = 0; c < 128; ++c) {
    float wu1 = w1[c * 512 + d1];
    float wu2 = w1[c * 512 + d2];
    float wv1 = w1[(c + 128) * 512 + d1];
    float wv2 = w1[(c + 128) * 512 + d2];
#pragma unroll
    for (int r = 0; r < 8; ++r) {
      float xv = xs[r * 128 + c];
      au0[r] = fmaf(xv, wu1, au0[r]);
      au1[r] = fmaf(xv, wu2, au1[r]);
      av0[r] = fmaf(xv, wv1, av0[r]);
      av1[r] = fmaf(xv, wv2, av1[r]);
    }
  }
#pragma unroll
  for (int r = 0; r < 8; ++r) {
    u[(size_t)(r0 + r) * 512 + d1] = au0[r];
    u[(size_t)(r0 + r) * 512 + d2] = au1[r];
    v[(size_t)(r0 + r) * 512 + d1] = av0[r];
    v[(size_t)(r0 + r) * 512 + d2] = av1[r];
  }
}

// ---------------- K2: w2t[n][k] = bf16(w2[k][n])  (256x512) -------------
__global__ __launch_bounds__(256) void k_w2t(const float* __restrict__ w2,
                                             __bf16* __restrict__ w2t) {
  int n = blockIdx.x;
  int t = threadIdx.x;
  w2t[(size_t)n * 512 + t]       = (__bf16)w2[(size_t)t * 256 + n];
  w2t[(size_t)n * 512 + t + 256] = (__bf16)w2[(size_t)(t + 256) * 256 + n];
}

// ---------------- K3: pwt[o][l] = pool_w[l][o]  (256x4096) --------------
__global__ __launch_bounds__(256) void k_pwt(const float* __restrict__ pw,
                                             float* __restrict__ pwt) {
  int o = blockIdx.x;
  int t = threadIdx.x;
#pragma unroll
  for (int it = 0; it < 16; ++it) {
    int l = it * 256 + t;
    pwt[(size_t)o * 4096 + l] = pw[(size_t)l * 256 + o];
  }
}

// ------- K4: fused h=relu(u_i+v_j) -> bf16 MFMA @ w2t -> f16 y^T --------
// K-chunked (4 x 64x128 h chunks, 18KB LDS) + XCD-bijective block swizzle
__global__ __launch_bounds__(256, 2) void k_gemm(const float* __restrict__ u,
                                                 const float* __restrict__ v,
                                                 const __bf16* __restrict__ w2t,
                                                 const float* __restrict__ b2,
                                                 unsigned short* __restrict__ yt) {
  __shared__ __bf16 hl[64 * 128];  // 16 KiB chunk, XOR-swizzled rows
  __shared__ float ul[512];
  int t = threadIdx.x;
  int n0 = blockIdx.x;
  int bid = (n0 & 7) * 256 + (n0 >> 3);  // same-b blocks -> same XCD
  int b = bid >> 6, i = bid & 63;
  if (t < 128) ((float4*)ul)[t] = ((const float4*)(u + (size_t)(b * 64 + i) * 512))[t];
  int w = t >> 6, l = t & 63;
  int lr = l & 15, lg = l >> 4;
  f32x4 acc[4][4];
  const __bf16* bptr[4];
#pragma unroll
  for (int ni = 0; ni < 4; ++ni) {
    int col = w * 64 + ni * 16 + lr;
    bptr[ni] = w2t + (size_t)col * 512 + lg * 8;
    float bias = b2[col];
    f32x4 cinit = {bias, bias, bias, bias};
#pragma unroll
    for (int mi = 0; mi < 4; ++mi) acc[mi][ni] = cinit;
  }
  int j = t >> 2, q = t & 3;
  const float* vrow = v + (size_t)(b * 64 + j) * 512;
#pragma unroll 1
  for (int c = 0; c < 4; ++c) {
    __syncthreads();  // hl reusable (and ul ready on c=0)
#pragma unroll
    for (int it = 0; it < 4; ++it) {
      int d0 = c * 128 + q * 32 + it * 8;
      float4 va = *(const float4*)(vrow + d0);
      float4 vb = *(const float4*)(vrow + d0 + 4);
      bf16x8 hv;
      hv[0] = (__bf16)fmaxf(ul[d0 + 0] + va.x, 0.f);
      hv[1] = (__bf16)fmaxf(ul[d0 + 1] + va.y, 0.f);
      hv[2] = (__bf16)fmaxf(ul[d0 + 2] + va.z, 0.f);
      hv[3] = (__bf16)fmaxf(ul[d0 + 3] + va.w, 0.f);
      hv[4] = (__bf16)fmaxf(ul[d0 + 4] + vb.x, 0.f);
      hv[5] = (__bf16)fmaxf(ul[d0 + 5] + vb.y, 0.f);
      hv[6] = (__bf16)fmaxf(ul[d0 + 6] + vb.z, 0.f);
      hv[7] = (__bf16)fmaxf(ul[d0 + 7] + vb.w, 0.f);
      int e = j * 128 + q * 32 + it * 8;
      *(bf16x8*)(hl + (e ^ ((j & 7) << 3))) = hv;
    }
    __syncthreads();
#pragma unroll
    for (int kk = 0; kk < 4; ++kk) {
      int kb = kk * 32 + lg * 8;
      bf16x8 af[4];
#pragma unroll
      for (int mi = 0; mi < 4; ++mi) {
        int row = mi * 16 + lr;
        int e = row * 128 + kb;
        af[mi] = *(const bf16x8*)(hl + (e ^ ((row & 7) << 3)));
      }
      bf16x8 bfv[4];
#pragma unroll
      for (int ni = 0; ni < 4; ++ni) bfv[ni] = *(const bf16x8*)(bptr[ni] + c * 128 + kk * 32);
#pragma unroll
      for (int mi = 0; mi < 4; ++mi)
#pragma unroll
        for (int ni = 0; ni < 4; ++ni)
          acc[mi][ni] = __builtin_amdgcn_mfma_f32_16x16x32_bf16(af[mi], bfv[ni], acc[mi][ni], 0, 0, 0);
    }
  }
  // epilogue: col=lane&15, row=(lane>>4)*4+reg -> f16 pack -> 8B store
#pragma unroll
  for (int ni = 0; ni < 4; ++ni) {
    int col = w * 64 + ni * 16 + lr;
    unsigned short* colbase = yt + (size_t)(b * 256 + col) * 4096 + (size_t)i * 64;
#pragma unroll
    for (int mi = 0; mi < 4; ++mi) {
      f32x4 vv = acc[mi][ni];
      uint2 st;
      st.x = pkrtz(vv[0], vv[1]);
      st.y = pkrtz(vv[2], vv[3]);
      *(uint2*)(colbase + mi * 16 + lg * 4) = st;
    }
  }
}

// -------- K5: packed-f16 monotone bitonic sort (2 cols/block) -----------
template <int M, int HB>
static __device__ __forceinline__ void intra(int* a) {
#pragma unroll
  for (int e = 0; e < 16; ++e)
    if ((e & HB) == 0) {
      int f = e ^ M;
      int lo = pkmin(a[e], a[f]);
      int hi = pkmax(a[e], a[f]);
      a[e] = lo;
      a[f] = hi;
    }
}

// cross-lane exchange via DPP (VALU pipe): CTRL = quad_perm/mirror/ror enc
template <int CTRL, bool FLIP>
static __device__ __forceinline__ void xdpp(int* a, bool km) {
  int r[16];
#pragma unroll
  for (int e = 0; e < 16; ++e)
    r[e] = __builtin_amdgcn_mov_dpp(a[FLIP ? (e ^ 15) : e], CTRL, 0xf, 0xf, true);
#pragma unroll
  for (int e = 0; e < 16; ++e) a[e] = km ? pkmin(a[e], r[e]) : pkmax(a[e], r[e]);
}
#define DPP_X1 0xB1   // quad_perm [1,0,3,2]  : lane^1
#define DPP_X2 0x4E   // quad_perm [2,3,0,1]  : lane^2
#define DPP_X3 0x1B   // quad_perm [3,2,1,0]  : lane^3
#define DPP_X7 0x141  // row_half_mirror      : lane^7
#define DPP_X8 0x128  // row_ror:8            : lane^8
#define DPP_XF 0x140  // row_mirror           : lane^15

// cross-lane pass within wave via ds_bpermute (masks 4,16,31,32,63)
template <bool FLIP>
static __device__ __forceinline__ void xw(int* a, int tm, bool km, int l) {
  int paddr = (l ^ tm) << 2;
  int r[16];
#pragma unroll
  for (int e = 0; e < 16; ++e)
    r[e] = __builtin_amdgcn_ds_bpermute(paddr, a[FLIP ? (e ^ 15) : e]);
#pragma unroll
  for (int e = 0; e < 16; ++e) a[e] = km ? pkmin(a[e], r[e]) : pkmax(a[e], r[e]);
}

// cross-wave pass via LDS (partner thread = t ^ tm, tm >= 64)
template <bool FLIP>
static __device__ __forceinline__ void xl(int* a, int tm, bool km, int t, int* sl) {
  __syncthreads();
#pragma unroll
  for (int e = 0; e < 16; ++e) sl[e * 256 + t] = a[e];
  __syncthreads();
  int pt = t ^ tm;
  int r[16];
#pragma unroll
  for (int e = 0; e < 16; ++e) r[e] = sl[(FLIP ? (e ^ 15) : e) * 256 + pt];
#pragma unroll
  for (int e = 0; e < 16; ++e) a[e] = km ? pkmin(a[e], r[e]) : pkmax(a[e], r[e]);
}

__global__ __launch_bounds__(256) void k_sortpool(const unsigned short* __restrict__ yt,
                                                  const float* __restrict__ pwt,
                                                  float* __restrict__ out) {
  __shared__ int sl[4096];
  __shared__ float red[8];
  int t = threadIdx.x;
  int l = t & 63;
  int b = blockIdx.x >> 7, p = blockIdx.x & 127;
  int o0 = p * 2, o1 = p * 2 + 1;
  const uint4* c0 = (const uint4*)(yt + (size_t)(b * 256 + o0) * 4096 + t * 16);
  const uint4* c1 = (const uint4*)(yt + (size_t)(b * 256 + o1) * 4096 + t * 16);
  uint4 A0 = c0[0], A1 = c0[1], B0 = c1[0], B1 = c1[1];
  unsigned cw0[8] = {A0.x, A0.y, A0.z, A0.w, A1.x, A1.y, A1.z, A1.w};
  unsigned cw1[8] = {B0.x, B0.y, B0.z, B0.w, B1.x, B1.y, B1.z, B1.w};
  int a[16];
#pragma unroll
  for (int q = 0; q < 8; ++q) {
    a[2 * q]     = (int)((cw0[q] & 0xffffu) | (cw1[q] << 16));
    a[2 * q + 1] = (int)((cw0[q] >> 16) | (cw1[q] & 0xffff0000u));
  }
  // intra stages k=1..8
  intra<1, 1>(a);
  intra<3, 2>(a); intra<1, 1>(a);
  intra<7, 4>(a); intra<2, 2>(a); intra<1, 1>(a);
  intra<15, 8>(a); intra<4, 4>(a); intra<2, 2>(a); intra<1, 1>(a);
#define INTRA4 intra<8, 8>(a); intra<4, 4>(a); intra<2, 2>(a); intra<1, 1>(a)
  // k=16
  xdpp<DPP_X1, true>(a, !(t & 1)); INTRA4;
  // k=32
  xdpp<DPP_X3, true>(a, !(t & 2)); xdpp<DPP_X1, false>(a, !(t & 1)); INTRA4;
  // k=64
  xdpp<DPP_X7, true>(a, !(t & 4)); xdpp<DPP_X2, false>(a, !(t & 2));
  xdpp<DPP_X1, false>(a, !(t & 1)); INTRA4;
  // k=128
  xdpp<DPP_XF, true>(a, !(t & 8)); xw<false>(a, 4, !(t & 4), l);
  xdpp<DPP_X2, false>(a, !(t & 2)); xdpp<DPP_X1, false>(a, !(t & 1)); INTRA4;
  // k=256
  xw<true>(a, 31, !(t & 16), l); xdpp<DPP_X8, false>(a, !(t & 8));
  xw<false>(a, 4, !(t & 4), l); xdpp<DPP_X2, false>(a, !(t & 2));
  xdpp<DPP_X1, false>(a, !(t & 1)); INTRA4;
  // k=512
  xw<true>(a, 63, !(t & 32), l); xw<false>(a, 16, !(t & 16), l);
  xdpp<DPP_X8, false>(a, !(t & 8)); xw<false>(a, 4, !(t & 4), l);
  xdpp<DPP_X2, false>(a, !(t & 2)); xdpp<DPP_X1, false>(a, !(t & 1)); INTRA4;
  // k=1024
  xl<true>(a, 127, !(t & 64), t, sl);
  xw<false>(a, 32, !(t & 32), l); xw<false>(a, 16, !(t & 16), l);
  xdpp<DPP_X8, false>(a, !(t & 8)); xw<false>(a, 4, !(t & 4), l);
  xdpp<DPP_X2, false>(a, !(t & 2)); xdpp<DPP_X1, false>(a, !(t & 1)); INTRA4;
  // k=2048
  xl<true>(a, 255, !(t & 128), t, sl);
  xl<false>(a, 64, !(t & 64), t, sl);
  xw<false>(a, 32, !(t & 32), l); xw<false>(a, 16, !(t & 16), l);
  xdpp<DPP_X8, false>(a, !(t & 8)); xw<false>(a, 4, !(t & 4), l);
  xdpp<DPP_X2, false>(a, !(t & 2)); xdpp<DPP_X1, false>(a, !(t & 1)); INTRA4;
#undef INTRA4
  // rank-weighted sum: rank of a[e] is 16t+e; lo half -> o0, hi half -> o1
  const float* pw0 = pwt + (size_t)o0 * 4096 + t * 16;
  const float* pw1 = pwt + (size_t)o1 * 4096 + t * 16;
  float s0 = 0.f, s1 = 0.f;
#pragma unroll
  for (int e = 0; e < 16; ++e) {
    h2 v2 = ih2(a[e]);
    s0 = fmaf((float)v2[0], pw0[e], s0);
    s1 = fmaf((float)v2[1], pw1[e], s1);
  }
#pragma unroll
  for (int off = 32; off > 0; off >>= 1) {
    s0 += __shfl_xor(s0, off);
    s1 += __shfl_xor(s1, off);
  }
  int wv = t >> 6;
  if (l == 0) { red[wv * 2] = s0; red[wv * 2 + 1] = s1; }
  __syncthreads();
  if (t == 0) out[b * 256 + o0] = red[0] + red[2] + red[4] + red[6];
  if (t == 1) out[b * 256 + o1] = red[1] + red[3] + red[5] + red[7];
}

extern "C" void kernel_launch(void* const* d_in, const int* in_sizes, int n_in,
                              void* d_out, int out_size, void* d_ws, size_t ws_size,
                              hipStream_t stream) {
  const float* x  = (const float*)d_in[0];
  const float* w1 = (const float*)d_in[1];
  const float* b1 = (const float*)d_in[2];
  const float* w2 = (const float*)d_in[3];
  const float* b2 = (const float*)d_in[4];
  const float* pw = (const float*)d_in[5];
  char* ws = (char*)d_ws;
  float*  u   = (float*)ws;                                        // 4 MiB
  float*  v   = (float*)(ws + (4u << 20));                         // 4 MiB
  __bf16* w2t = (__bf16*)(ws + (8u << 20));                        // 256 KiB
  float*  pwt = (float*)(ws + (8u << 20) + (256u << 10));          // 4 MiB
  unsigned short* yt = (unsigned short*)(ws + (12u << 20) + (256u << 10));  // 64 MiB f16
  float* out = (float*)d_out;

  k_uv<<<dim3(256), dim3(256), 0, stream>>>(x, w1, b1, u, v);
  k_w2t<<<dim3(256), dim3(256), 0, stream>>>(w2, w2t);
  k_pwt<<<dim3(256), dim3(256), 0, stream>>>(pw, pwt);
  k_gemm<<<dim3(2048), dim3(256), 0, stream>>>(u, v, w2t, b2, yt);
  k_sortpool<<<dim3(4096), dim3(256), 0, stream>>>(yt, pwt, out);
}

// Round 5
// 171.453 us; speedup vs baseline: 2.2750x; 1.3441x over previous
//
#include <hip/hip_runtime.h>
#include <hip/hip_bf16.h>
#include <hip/hip_fp16.h>

typedef __attribute__((ext_vector_type(4))) float f32x4;
typedef _Float16 h8 __attribute__((ext_vector_type(8)));
typedef int i32x4 __attribute__((ext_vector_type(4)));
typedef _Float16 h2 __attribute__((ext_vector_type(2)));

static __device__ __forceinline__ h2 ih2(int x) { return __builtin_bit_cast(h2, x); }
static __device__ __forceinline__ unsigned pkrtz(float lo, float hi) {
  return __builtin_bit_cast(unsigned, __builtin_amdgcn_cvt_pkrtz(lo, hi));
}
static __device__ __forceinline__ int pkmin(int x, int y) {
  int d; asm("v_pk_min_f16 %0, %1, %2" : "=v"(d) : "v"(x), "v"(y)); return d;
}
static __device__ __forceinline__ int pkmax(int x, int y) {
  int d; asm("v_pk_max_f16 %0, %1, %2" : "=v"(d) : "v"(x), "v"(y)); return d;
}
static __device__ __forceinline__ int pkadd(int x, int y) {
  int d; asm("v_pk_add_f16 %0, %1, %2" : "=v"(d) : "v"(x), "v"(y)); return d;
}

// Problem constants: B=32, L=64, C=128, D=512, O=256, L2=4096

// ---------------- K1: u = f16(x@w1[:128] + b1) ; v = f16(x@w1[128:]) ----
__global__ __launch_bounds__(256) void k_uv(const float* __restrict__ x,
                                            const float* __restrict__ w1,
                                            const float* __restrict__ b1,
                                            _Float16* __restrict__ u,
                                            _Float16* __restrict__ v) {
  __shared__ float xs[8 * 128];
  int t = threadIdx.x;
  int r0 = blockIdx.x * 8;
  ((float4*)xs)[t] = ((const float4*)(x + (size_t)r0 * 128))[t];
  __syncthreads();
  int d1 = t, d2 = t + 256;
  float au0[8], au1[8], av0[8], av1[8];
  float bb1 = b1[d1], bb2 = b1[d2];
#pragma unroll
  for (int r = 0; r < 8; ++r) { au0[r] = bb1; au1[r] = bb2; av0[r] = 0.f; av1[r] = 0.f; }
#pragma unroll 4
  for (int c = 0; c < 128; ++c) {
    float wu1 = w1[c * 512 + d1];
    float wu2 = w1[c * 512 + d2];
    float wv1 = w1[(c + 128) * 512 + d1];
    float wv2 = w1[(c + 128) * 512 + d2];
#pragma unroll
    for (int r = 0; r < 8; ++r) {
      float xv = xs[r * 128 + c];
      au0[r] = fmaf(xv, wu1, au0[r]);
      au1[r] = fmaf(xv, wu2, au1[r]);
      av0[r] = fmaf(xv, wv1, av0[r]);
      av1[r] = fmaf(xv, wv2, av1[r]);
    }
  }
#pragma unroll
  for (int r = 0; r < 8; ++r) {
    u[(size_t)(r0 + r) * 512 + d1] = (_Float16)au0[r];
    u[(size_t)(r0 + r) * 512 + d2] = (_Float16)au1[r];
    v[(size_t)(r0 + r) * 512 + d1] = (_Float16)av0[r];
    v[(size_t)(r0 + r) * 512 + d2] = (_Float16)av1[r];
  }
}

// ---------------- K2: w2t[n][k] = f16(w2[k][n])  (256x512) --------------
__global__ __launch_bounds__(256) void k_w2t(const float* __restrict__ w2,
                                             _Float16* __restrict__ w2t) {
  int n = blockIdx.x;
  int t = threadIdx.x;
  w2t[(size_t)n * 512 + t]       = (_Float16)w2[(size_t)t * 256 + n];
  w2t[(size_t)n * 512 + t + 256] = (_Float16)w2[(size_t)(t + 256) * 256 + n];
}

// ---------------- K3: pwt[o][l] = pool_w[l][o]  (256x4096) --------------
__global__ __launch_bounds__(256) void k_pwt(const float* __restrict__ pw,
                                             float* __restrict__ pwt) {
  int o = blockIdx.x;
  int t = threadIdx.x;
#pragma unroll
  for (int it = 0; it < 16; ++it) {
    int l = it * 256 + t;
    pwt[(size_t)o * 4096 + l] = pw[(size_t)l * 256 + o];
  }
}

// ---- K4: register-built h = relu(u_i + v_j) -> f16 MFMA -> f16 y^T -----
// block = (b, ig): 4 i-rows; v-tile 64x512 f16 in LDS (swizzled), 1 barrier
__global__ __launch_bounds__(256, 2) void k_gemm(const _Float16* __restrict__ u,
                                                 const _Float16* __restrict__ v,
                                                 const _Float16* __restrict__ w2t,
                                                 const float* __restrict__ b2,
                                                 unsigned short* __restrict__ yt) {
  __shared__ char vl[64 * 1024];  // 64 rows x 512 f16, XOR-swizzled
  __shared__ char ulm[4 * 1024];  // 4 u-rows x 512 f16
  int t = threadIdx.x;
  int n0 = blockIdx.x;                     // 512 blocks
  int bid = (n0 & 7) * 64 + (n0 >> 3);     // XCD-bijective: same-b same XCD
  int b = bid >> 4, ig = bid & 15;
  // stage v tile (64 KiB) coalesced, swizzled write
  {
    const char* vsrc = (const char*)(v + (size_t)b * 64 * 512);
#pragma unroll
    for (int it = 0; it < 16; ++it) {
      int f = it * 4096 + t * 16;
      uint4 d = *(const uint4*)(vsrc + f);
      int row = f >> 10;
      *(uint4*)(vl + (f ^ ((row & 7) << 4))) = d;
    }
    const char* usrc = (const char*)(u + (size_t)(b * 64 + ig * 4) * 512);
    int f = t * 16;
    *(uint4*)(ulm + f) = *(const uint4*)(usrc + f);
  }
  __syncthreads();
  int w = t >> 6, l = t & 63, lr = l & 15, lg = l >> 4;
  const _Float16* bptr[4];
  float bias[4];
#pragma unroll
  for (int ni = 0; ni < 4; ++ni) {
    int col = w * 64 + ni * 16 + lr;
    bptr[ni] = w2t + (size_t)col * 512 + lg * 8;
    bias[ni] = b2[col];
  }
#pragma unroll 1
  for (int ih = 0; ih < 2; ++ih) {  // i-pairs: i = ig*4 + ih*2 + {0,1}
    f32x4 acc[2][4][4];
#pragma unroll
    for (int ip = 0; ip < 2; ++ip)
#pragma unroll
      for (int mi = 0; mi < 4; ++mi)
#pragma unroll
        for (int ni = 0; ni < 4; ++ni) {
          float bv = bias[ni];
          f32x4 ci = {bv, bv, bv, bv};
          acc[ip][mi][ni] = ci;
        }
#pragma unroll 2
    for (int kk = 0; kk < 16; ++kk) {
      h8 bfv[4];
#pragma unroll
      for (int ni = 0; ni < 4; ++ni) bfv[ni] = *(const h8*)(bptr[ni] + kk * 32);
      i32x4 vf[4];
#pragma unroll
      for (int mi = 0; mi < 4; ++mi) {
        int row = mi * 16 + lr;
        int fb = row * 1024 + kk * 64 + lg * 16;
        vf[mi] = *(const i32x4*)(vl + (fb ^ ((row & 7) << 4)));
      }
#pragma unroll
      for (int ip = 0; ip < 2; ++ip) {
        i32x4 uf = *(const i32x4*)(ulm + (ih * 2 + ip) * 1024 + kk * 64 + lg * 16);
#pragma unroll
        for (int mi = 0; mi < 4; ++mi) {
          i32x4 aw;
#pragma unroll
          for (int q = 0; q < 4; ++q) aw[q] = pkmax(pkadd(uf[q], vf[mi][q]), 0);
          h8 af = __builtin_bit_cast(h8, aw);
#pragma unroll
          for (int ni = 0; ni < 4; ++ni)
            acc[ip][mi][ni] =
                __builtin_amdgcn_mfma_f32_16x16x32_f16(af, bfv[ni], acc[ip][mi][ni], 0, 0, 0);
        }
      }
    }
    // epilogue: col=lane&15, row=(lane>>4)*4+reg -> f16 pack -> 8B store
#pragma unroll
    for (int ip = 0; ip < 2; ++ip) {
      int i = ig * 4 + ih * 2 + ip;
#pragma unroll
      for (int ni = 0; ni < 4; ++ni) {
        int col = w * 64 + ni * 16 + lr;
        unsigned short* colbase = yt + (size_t)(b * 256 + col) * 4096 + (size_t)i * 64;
#pragma unroll
        for (int mi = 0; mi < 4; ++mi) {
          f32x4 vv = acc[ip][mi][ni];
          uint2 st;
          st.x = pkrtz(vv[0], vv[1]);
          st.y = pkrtz(vv[2], vv[3]);
          *(uint2*)(colbase + mi * 16 + lg * 4) = st;
        }
      }
    }
  }
}

// -------- K5: packed-f16 monotone bitonic sort (2 cols/block) -----------
template <int M, int HB>
static __device__ __forceinline__ void intra(int* a) {
#pragma unroll
  for (int e = 0; e < 16; ++e)
    if ((e & HB) == 0) {
      int f = e ^ M;
      int lo = pkmin(a[e], a[f]);
      int hi = pkmax(a[e], a[f]);
      a[e] = lo;
      a[f] = hi;
    }
}

template <int CTRL, bool FLIP>
static __device__ __forceinline__ void xdpp(int* a, bool km) {
  int r[16];
#pragma unroll
  for (int e = 0; e < 16; ++e)
    r[e] = __builtin_amdgcn_mov_dpp(a[FLIP ? (e ^ 15) : e], CTRL, 0xf, 0xf, true);
#pragma unroll
  for (int e = 0; e < 16; ++e) a[e] = km ? pkmin(a[e], r[e]) : pkmax(a[e], r[e]);
}
#define DPP_X1 0xB1   // quad_perm [1,0,3,2]  : lane^1
#define DPP_X2 0x4E   // quad_perm [2,3,0,1]  : lane^2
#define DPP_X3 0x1B   // quad_perm [3,2,1,0]  : lane^3
#define DPP_X7 0x141  // row_half_mirror      : lane^7
#define DPP_X8 0x128  // row_ror:8            : lane^8
#define DPP_XF 0x140  // row_mirror           : lane^15

template <bool FLIP>
static __device__ __forceinline__ void xw(int* a, int tm, bool km, int l) {
  int paddr = (l ^ tm) << 2;
  int r[16];
#pragma unroll
  for (int e = 0; e < 16; ++e)
    r[e] = __builtin_amdgcn_ds_bpermute(paddr, a[FLIP ? (e ^ 15) : e]);
#pragma unroll
  for (int e = 0; e < 16; ++e) a[e] = km ? pkmin(a[e], r[e]) : pkmax(a[e], r[e]);
}

template <bool FLIP>
static __device__ __forceinline__ void xl(int* a, int tm, bool km, int t, int* sl) {
  __syncthreads();
#pragma unroll
  for (int e = 0; e < 16; ++e) sl[e * 256 + t] = a[e];
  __syncthreads();
  int pt = t ^ tm;
  int r[16];
#pragma unroll
  for (int e = 0; e < 16; ++e) r[e] = sl[(FLIP ? (e ^ 15) : e) * 256 + pt];
#pragma unroll
  for (int e = 0; e < 16; ++e) a[e] = km ? pkmin(a[e], r[e]) : pkmax(a[e], r[e]);
}

__global__ __launch_bounds__(256) void k_sortpool(const unsigned short* __restrict__ yt,
                                                  const float* __restrict__ pwt,
                                                  float* __restrict__ out) {
  __shared__ int sl[4096];
  __shared__ float red[8];
  int t = threadIdx.x;
  int l = t & 63;
  int b = blockIdx.x >> 7, p = blockIdx.x & 127;
  int o0 = p * 2, o1 = p * 2 + 1;
  const uint4* c0 = (const uint4*)(yt + (size_t)(b * 256 + o0) * 4096 + t * 16);
  const uint4* c1 = (const uint4*)(yt + (size_t)(b * 256 + o1) * 4096 + t * 16);
  uint4 A0 = c0[0], A1 = c0[1], B0 = c1[0], B1 = c1[1];
  unsigned cw0[8] = {A0.x, A0.y, A0.z, A0.w, A1.x, A1.y, A1.z, A1.w};
  unsigned cw1[8] = {B0.x, B0.y, B0.z, B0.w, B1.x, B1.y, B1.z, B1.w};
  int a[16];
#pragma unroll
  for (int q = 0; q < 8; ++q) {
    a[2 * q]     = (int)((cw0[q] & 0xffffu) | (cw1[q] << 16));
    a[2 * q + 1] = (int)((cw0[q] >> 16) | (cw1[q] & 0xffff0000u));
  }
  intra<1, 1>(a);
  intra<3, 2>(a); intra<1, 1>(a);
  intra<7, 4>(a); intra<2, 2>(a); intra<1, 1>(a);
  intra<15, 8>(a); intra<4, 4>(a); intra<2, 2>(a); intra<1, 1>(a);
#define INTRA4 intra<8, 8>(a); intra<4, 4>(a); intra<2, 2>(a); intra<1, 1>(a)
  xdpp<DPP_X1, true>(a, !(t & 1)); INTRA4;
  xdpp<DPP_X3, true>(a, !(t & 2)); xdpp<DPP_X1, false>(a, !(t & 1)); INTRA4;
  xdpp<DPP_X7, true>(a, !(t & 4)); xdpp<DPP_X2, false>(a, !(t & 2));
  xdpp<DPP_X1, false>(a, !(t & 1)); INTRA4;
  xdpp<DPP_XF, true>(a, !(t & 8)); xw<false>(a, 4, !(t & 4), l);
  xdpp<DPP_X2, false>(a, !(t & 2)); xdpp<DPP_X1, false>(a, !(t & 1)); INTRA4;
  xw<true>(a, 31, !(t & 16), l); xdpp<DPP_X8, false>(a, !(t & 8));
  xw<false>(a, 4, !(t & 4), l); xdpp<DPP_X2, false>(a, !(t & 2));
  xdpp<DPP_X1, false>(a, !(t & 1)); INTRA4;
  xw<true>(a, 63, !(t & 32), l); xw<false>(a, 16, !(t & 16), l);
  xdpp<DPP_X8, false>(a, !(t & 8)); xw<false>(a, 4, !(t & 4), l);
  xdpp<DPP_X2, false>(a, !(t & 2)); xdpp<DPP_X1, false>(a, !(t & 1)); INTRA4;
  xl<true>(a, 127, !(t & 64), t, sl);
  xw<false>(a, 32, !(t & 32), l); xw<false>(a, 16, !(t & 16), l);
  xdpp<DPP_X8, false>(a, !(t & 8)); xw<false>(a, 4, !(t & 4), l);
  xdpp<DPP_X2, false>(a, !(t & 2)); xdpp<DPP_X1, false>(a, !(t & 1)); INTRA4;
  xl<true>(a, 255, !(t & 128), t, sl);
  xl<false>(a, 64, !(t & 64), t, sl);
  xw<false>(a, 32, !(t & 32), l); xw<false>(a, 16, !(t & 16), l);
  xdpp<DPP_X8, false>(a, !(t & 8)); xw<false>(a, 4, !(t & 4), l);
  xdpp<DPP_X2, false>(a, !(t & 2)); xdpp<DPP_X1, false>(a, !(t & 1)); INTRA4;
#undef INTRA4
  const float* pw0 = pwt + (size_t)o0 * 4096 + t * 16;
  const float* pw1 = pwt + (size_t)o1 * 4096 + t * 16;
  float s0 = 0.f, s1 = 0.f;
#pragma unroll
  for (int e = 0; e < 16; ++e) {
    h2 v2 = ih2(a[e]);
    s0 = fmaf((float)v2[0], pw0[e], s0);
    s1 = fmaf((float)v2[1], pw1[e], s1);
  }
#pragma unroll
  for (int off = 32; off > 0; off >>= 1) {
    s0 += __shfl_xor(s0, off);
    s1 += __shfl_xor(s1, off);
  }
  int wv = t >> 6;
  if (l == 0) { red[wv * 2] = s0; red[wv * 2 + 1] = s1; }
  __syncthreads();
  if (t == 0) out[b * 256 + o0] = red[0] + red[2] + red[4] + red[6];
  if (t == 1) out[b * 256 + o1] = red[1] + red[3] + red[5] + red[7];
}

extern "C" void kernel_launch(void* const* d_in, const int* in_sizes, int n_in,
                              void* d_out, int out_size, void* d_ws, size_t ws_size,
                              hipStream_t stream) {
  const float* x  = (const float*)d_in[0];
  const float* w1 = (const float*)d_in[1];
  const float* b1 = (const float*)d_in[2];
  const float* w2 = (const float*)d_in[3];
  const float* b2 = (const float*)d_in[4];
  const float* pw = (const float*)d_in[5];
  char* ws = (char*)d_ws;
  _Float16* u   = (_Float16*)ws;                                   // 2 MiB
  _Float16* v   = (_Float16*)(ws + (2u << 20));                    // 2 MiB
  _Float16* w2t = (_Float16*)(ws + (4u << 20));                    // 256 KiB
  float*    pwt = (float*)(ws + (5u << 20));                       // 4 MiB
  unsigned short* yt = (unsigned short*)(ws + (9u << 20));         // 64 MiB f16
  float* out = (float*)d_out;

  k_uv<<<dim3(256), dim3(256), 0, stream>>>(x, w1, b1, u, v);
  k_w2t<<<dim3(256), dim3(256), 0, stream>>>(w2, w2t);
  k_pwt<<<dim3(256), dim3(256), 0, stream>>>(pw, pwt);
  k_gemm<<<dim3(512), dim3(256), 0, stream>>>(u, v, w2t, b2, yt);
  k_sortpool<<<dim3(4096), dim3(256), 0, stream>>>(yt, pwt, out);
}

// Round 6
// 153.091 us; speedup vs baseline: 2.5479x; 1.1199x over previous
//
#include <hip/hip_runtime.h>
#include <hip/hip_bf16.h>
#include <hip/hip_fp16.h>

typedef __attribute__((ext_vector_type(4))) float f32x4;
typedef _Float16 h8 __attribute__((ext_vector_type(8)));
typedef int i32x4 __attribute__((ext_vector_type(4)));
typedef _Float16 h2 __attribute__((ext_vector_type(2)));

static __device__ __forceinline__ h2 ih2(int x) { return __builtin_bit_cast(h2, x); }
static __device__ __forceinline__ unsigned pkrtz(float lo, float hi) {
  return __builtin_bit_cast(unsigned, __builtin_amdgcn_cvt_pkrtz(lo, hi));
}
static __device__ __forceinline__ int pkmin(int x, int y) {
  int d; asm("v_pk_min_f16 %0, %1, %2" : "=v"(d) : "v"(x), "v"(y)); return d;
}
static __device__ __forceinline__ int pkmax(int x, int y) {
  int d; asm("v_pk_max_f16 %0, %1, %2" : "=v"(d) : "v"(x), "v"(y)); return d;
}
static __device__ __forceinline__ int pkadd(int x, int y) {
  int d; asm("v_pk_add_f16 %0, %1, %2" : "=v"(d) : "v"(x), "v"(y)); return d;
}

// Problem constants: B=32, L=64, C=128, D=512, O=256, L2=4096

// ---------------- K1: u = f16(x@w1[:128] + b1) ; v = f16(x@w1[128:]) ----
__global__ __launch_bounds__(256) void k_uv(const float* __restrict__ x,
                                            const float* __restrict__ w1,
                                            const float* __restrict__ b1,
                                            _Float16* __restrict__ u,
                                            _Float16* __restrict__ v) {
  __shared__ float xs[8 * 128];
  int t = threadIdx.x;
  int r0 = blockIdx.x * 8;
  ((float4*)xs)[t] = ((const float4*)(x + (size_t)r0 * 128))[t];
  __syncthreads();
  int d1 = t, d2 = t + 256;
  float au0[8], au1[8], av0[8], av1[8];
  float bb1 = b1[d1], bb2 = b1[d2];
#pragma unroll
  for (int r = 0; r < 8; ++r) { au0[r] = bb1; au1[r] = bb2; av0[r] = 0.f; av1[r] = 0.f; }
#pragma unroll 4
  for (int c = 0; c < 128; ++c) {
    float wu1 = w1[c * 512 + d1];
    float wu2 = w1[c * 512 + d2];
    float wv1 = w1[(c + 128) * 512 + d1];
    float wv2 = w1[(c + 128) * 512 + d2];
#pragma unroll
    for (int r = 0; r < 8; ++r) {
      float xv = xs[r * 128 + c];
      au0[r] = fmaf(xv, wu1, au0[r]);
      au1[r] = fmaf(xv, wu2, au1[r]);
      av0[r] = fmaf(xv, wv1, av0[r]);
      av1[r] = fmaf(xv, wv2, av1[r]);
    }
  }
#pragma unroll
  for (int r = 0; r < 8; ++r) {
    u[(size_t)(r0 + r) * 512 + d1] = (_Float16)au0[r];
    u[(size_t)(r0 + r) * 512 + d2] = (_Float16)au1[r];
    v[(size_t)(r0 + r) * 512 + d1] = (_Float16)av0[r];
    v[(size_t)(r0 + r) * 512 + d2] = (_Float16)av1[r];
  }
}

// ---------------- K2: w2t[n][k] = f16(w2[k][n])  (256x512) --------------
__global__ __launch_bounds__(256) void k_w2t(const float* __restrict__ w2,
                                             _Float16* __restrict__ w2t) {
  int n = blockIdx.x;
  int t = threadIdx.x;
  w2t[(size_t)n * 512 + t]       = (_Float16)w2[(size_t)t * 256 + n];
  w2t[(size_t)n * 512 + t + 256] = (_Float16)w2[(size_t)(t + 256) * 256 + n];
}

// ---------------- K3: pwt[o][l] = pool_w[l][o]  (256x4096) --------------
__global__ __launch_bounds__(256) void k_pwt(const float* __restrict__ pw,
                                             float* __restrict__ pwt) {
  int o = blockIdx.x;
  int t = threadIdx.x;
#pragma unroll
  for (int it = 0; it < 16; ++it) {
    int l = it * 256 + t;
    pwt[(size_t)o * 4096 + l] = pw[(size_t)l * 256 + o];
  }
}

// ---- K4: register-built h = relu(u_i + v_j) -> f16 MFMA -> f16 y^T -----
__global__ __launch_bounds__(256, 2) void k_gemm(const _Float16* __restrict__ u,
                                                 const _Float16* __restrict__ v,
                                                 const _Float16* __restrict__ w2t,
                                                 const float* __restrict__ b2,
                                                 unsigned short* __restrict__ yt) {
  __shared__ char vl[64 * 1024];  // 64 rows x 512 f16, XOR-swizzled
  __shared__ char ulm[4 * 1024];  // 4 u-rows x 512 f16
  int t = threadIdx.x;
  int n0 = blockIdx.x;                     // 512 blocks
  int bid = (n0 & 7) * 64 + (n0 >> 3);     // XCD-bijective: same-b same XCD
  int b = bid >> 4, ig = bid & 15;
  {
    const char* vsrc = (const char*)(v + (size_t)b * 64 * 512);
#pragma unroll
    for (int it = 0; it < 16; ++it) {
      int f = it * 4096 + t * 16;
      uint4 d = *(const uint4*)(vsrc + f);
      int row = f >> 10;
      *(uint4*)(vl + (f ^ ((row & 7) << 4))) = d;
    }
    const char* usrc = (const char*)(u + (size_t)(b * 64 + ig * 4) * 512);
    int f = t * 16;
    *(uint4*)(ulm + f) = *(const uint4*)(usrc + f);
  }
  __syncthreads();
  int w = t >> 6, l = t & 63, lr = l & 15, lg = l >> 4;
  const _Float16* bptr[4];
  float bias[4];
#pragma unroll
  for (int ni = 0; ni < 4; ++ni) {
    int col = w * 64 + ni * 16 + lr;
    bptr[ni] = w2t + (size_t)col * 512 + lg * 8;
    bias[ni] = b2[col];
  }
#pragma unroll 1
  for (int ih = 0; ih < 2; ++ih) {  // i-pairs: i = ig*4 + ih*2 + {0,1}
    f32x4 acc[2][4][4];
#pragma unroll
    for (int ip = 0; ip < 2; ++ip)
#pragma unroll
      for (int mi = 0; mi < 4; ++mi)
#pragma unroll
        for (int ni = 0; ni < 4; ++ni) {
          float bv = bias[ni];
          f32x4 ci = {bv, bv, bv, bv};
          acc[ip][mi][ni] = ci;
        }
#pragma unroll 2
    for (int kk = 0; kk < 16; ++kk) {
      h8 bfv[4];
#pragma unroll
      for (int ni = 0; ni < 4; ++ni) bfv[ni] = *(const h8*)(bptr[ni] + kk * 32);
      i32x4 vf[4];
#pragma unroll
      for (int mi = 0; mi < 4; ++mi) {
        int row = mi * 16 + lr;
        int fb = row * 1024 + kk * 64 + lg * 16;
        vf[mi] = *(const i32x4*)(vl + (fb ^ ((row & 7) << 4)));
      }
#pragma unroll
      for (int ip = 0; ip < 2; ++ip) {
        i32x4 uf = *(const i32x4*)(ulm + (ih * 2 + ip) * 1024 + kk * 64 + lg * 16);
#pragma unroll
        for (int mi = 0; mi < 4; ++mi) {
          i32x4 aw;
#pragma unroll
          for (int q = 0; q < 4; ++q) aw[q] = pkmax(pkadd(uf[q], vf[mi][q]), 0);
          h8 af = __builtin_bit_cast(h8, aw);
#pragma unroll
          for (int ni = 0; ni < 4; ++ni)
            acc[ip][mi][ni] =
                __builtin_amdgcn_mfma_f32_16x16x32_f16(af, bfv[ni], acc[ip][mi][ni], 0, 0, 0);
        }
      }
    }
#pragma unroll
    for (int ip = 0; ip < 2; ++ip) {
      int i = ig * 4 + ih * 2 + ip;
#pragma unroll
      for (int ni = 0; ni < 4; ++ni) {
        int col = w * 64 + ni * 16 + lr;
        unsigned short* colbase = yt + (size_t)(b * 256 + col) * 4096 + (size_t)i * 64;
#pragma unroll
        for (int mi = 0; mi < 4; ++mi) {
          f32x4 vv = acc[ip][mi][ni];
          uint2 st;
          st.x = pkrtz(vv[0], vv[1]);
          st.y = pkrtz(vv[2], vv[3]);
          *(uint2*)(colbase + mi * 16 + lg * 4) = st;
        }
      }
    }
  }
}

// ----- K5: E=64 single-wave packed-f16 bitonic sort + pool (no LDS) -----
#define DPP_X1 0xB1   // quad_perm [1,0,3,2]  : lane^1
#define DPP_X2 0x4E   // quad_perm [2,3,0,1]  : lane^2
#define DPP_X3 0x1B   // quad_perm [3,2,1,0]  : lane^3
#define DPP_X7 0x141  // row_half_mirror      : lane^7
#define DPP_X8 0x128  // row_ror:8            : lane^8
#define DPP_XF 0x140  // row_mirror           : lane^15

// intra-register CE pass: pairs (e, e^M), min at low index
template <int M, int HB>
static __device__ __forceinline__ void intra(int* a) {
#pragma unroll
  for (int e = 0; e < 64; ++e)
    if ((e & HB) == 0) {
      int f = e ^ M;
      int lo = pkmin(a[e], a[f]);
      int hi = pkmax(a[e], a[f]);
      a[e] = lo;
      a[f] = hi;
    }
}

// clean cross pass via DPP (same e, partner lane)
template <int CTRL>
static __device__ __forceinline__ void cdpp(int* a, bool km) {
#pragma unroll
  for (int e = 0; e < 64; ++e) {
    int r = __builtin_amdgcn_mov_dpp(a[e], CTRL, 0xf, 0xf, true);
    int mn = pkmin(a[e], r), mx = pkmax(a[e], r);
    a[e] = km ? mn : mx;
  }
}

// flip cross pass via DPP (e^63, partner lane)
template <int CTRL>
static __device__ __forceinline__ void fdpp(int* a, bool km) {
#pragma unroll
  for (int e = 0; e < 32; ++e) {
    int f = e ^ 63;
    int r0 = __builtin_amdgcn_mov_dpp(a[f], CTRL, 0xf, 0xf, true);
    int r1 = __builtin_amdgcn_mov_dpp(a[e], CTRL, 0xf, 0xf, true);
    int mn0 = pkmin(a[e], r0), mx0 = pkmax(a[e], r0);
    int mn1 = pkmin(a[f], r1), mx1 = pkmax(a[f], r1);
    a[e] = km ? mn0 : mx0;
    a[f] = km ? mn1 : mx1;
  }
}

// clean cross pass via ds_bpermute
static __device__ __forceinline__ void cbp(int* a, int tm, bool km, int t) {
  int paddr = ((t ^ tm) & 63) << 2;
#pragma unroll
  for (int e = 0; e < 64; ++e) {
    int r = __builtin_amdgcn_ds_bpermute(paddr, a[e]);
    int mn = pkmin(a[e], r), mx = pkmax(a[e], r);
    a[e] = km ? mn : mx;
  }
}

// flip cross pass via ds_bpermute (e^63)
static __device__ __forceinline__ void fbp(int* a, int tm, bool km, int t) {
  int paddr = ((t ^ tm) & 63) << 2;
#pragma unroll
  for (int e = 0; e < 32; ++e) {
    int f = e ^ 63;
    int r0 = __builtin_amdgcn_ds_bpermute(paddr, a[f]);
    int r1 = __builtin_amdgcn_ds_bpermute(paddr, a[e]);
    int mn0 = pkmin(a[e], r0), mx0 = pkmax(a[e], r0);
    int mn1 = pkmin(a[f], r1), mx1 = pkmax(a[f], r1);
    a[e] = km ? mn0 : mx0;
    a[f] = km ? mn1 : mx1;
  }
}

__global__ __launch_bounds__(64) void k_sortpool(const unsigned short* __restrict__ yt,
                                                 const float* __restrict__ pwt,
                                                 float* __restrict__ out) {
  int t = threadIdx.x;  // lane 0..63 (one wave per block)
  int b = blockIdx.x >> 7, p = blockIdx.x & 127;
  int o0 = p * 2, o1 = o0 + 1;
  const uint4* c0 = (const uint4*)(yt + (size_t)(b * 256 + o0) * 4096 + t * 64);
  const uint4* c1 = (const uint4*)(yt + (size_t)(b * 256 + o1) * 4096 + t * 64);
  int a[64];
#pragma unroll
  for (int q = 0; q < 8; ++q) {  // 8 elems per uint4 per column
    uint4 x0 = c0[q], x1 = c1[q];
    unsigned w0[4] = {x0.x, x0.y, x0.z, x0.w};
    unsigned w1[4] = {x1.x, x1.y, x1.z, x1.w};
#pragma unroll
    for (int r = 0; r < 4; ++r) {
      a[q * 8 + 2 * r]     = (int)((w0[r] & 0xffffu) | (w1[r] << 16));
      a[q * 8 + 2 * r + 1] = (int)((w0[r] >> 16) | (w1[r] & 0xffff0000u));
    }
  }
  // stages s1..s6 (runs <= 64): pure in-register
  intra<1, 1>(a);
  intra<3, 2>(a); intra<1, 1>(a);
  intra<7, 4>(a); intra<2, 2>(a); intra<1, 1>(a);
  intra<15, 8>(a); intra<4, 4>(a); intra<2, 2>(a); intra<1, 1>(a);
  intra<31, 16>(a); intra<8, 8>(a); intra<4, 4>(a); intra<2, 2>(a); intra<1, 1>(a);
  intra<63, 32>(a); intra<16, 16>(a); intra<8, 8>(a); intra<4, 4>(a);
  intra<2, 2>(a); intra<1, 1>(a);
#define CLEAN6 intra<32, 32>(a); intra<16, 16>(a); intra<8, 8>(a); \
               intra<4, 4>(a); intra<2, 2>(a); intra<1, 1>(a)
  // s7 -> 128-runs
  fdpp<DPP_X1>(a, !(t & 1)); CLEAN6;
  // s8 -> 256
  fdpp<DPP_X3>(a, !(t & 2)); cdpp<DPP_X1>(a, !(t & 1)); CLEAN6;
  // s9 -> 512
  fdpp<DPP_X7>(a, !(t & 4)); cdpp<DPP_X2>(a, !(t & 2)); cdpp<DPP_X1>(a, !(t & 1)); CLEAN6;
  // s10 -> 1024
  fdpp<DPP_XF>(a, !(t & 8)); cbp(a, 4, !(t & 4), t);
  cdpp<DPP_X2>(a, !(t & 2)); cdpp<DPP_X1>(a, !(t & 1)); CLEAN6;
  // s11 -> 2048
  fbp(a, 31, !(t & 16), t); cdpp<DPP_X8>(a, !(t & 8)); cbp(a, 4, !(t & 4), t);
  cdpp<DPP_X2>(a, !(t & 2)); cdpp<DPP_X1>(a, !(t & 1)); CLEAN6;
  // s12 -> 4096
  fbp(a, 63, !(t & 32), t); cbp(a, 16, !(t & 16), t); cdpp<DPP_X8>(a, !(t & 8));
  cbp(a, 4, !(t & 4), t); cdpp<DPP_X2>(a, !(t & 2)); cdpp<DPP_X1>(a, !(t & 1)); CLEAN6;
#undef CLEAN6
  // rank-weighted sum: rank of a[e] is 64t+e; lo half -> o0, hi half -> o1
  const float4* pw0 = (const float4*)(pwt + (size_t)o0 * 4096 + t * 64);
  const float4* pw1 = (const float4*)(pwt + (size_t)o1 * 4096 + t * 64);
  float s0 = 0.f, s1 = 0.f;
#pragma unroll
  for (int q = 0; q < 16; ++q) {
    float4 w0 = pw0[q], w1 = pw1[q];
    float k0[4] = {w0.x, w0.y, w0.z, w0.w};
    float k1[4] = {w1.x, w1.y, w1.z, w1.w};
#pragma unroll
    for (int r = 0; r < 4; ++r) {
      h2 v2 = ih2(a[q * 4 + r]);
      s0 = fmaf((float)v2[0], k0[r], s0);
      s1 = fmaf((float)v2[1], k1[r], s1);
    }
  }
#pragma unroll
  for (int off = 32; off > 0; off >>= 1) {
    s0 += __shfl_xor(s0, off);
    s1 += __shfl_xor(s1, off);
  }
  if (t == 0) {
    out[b * 256 + o0] = s0;
    out[b * 256 + o1] = s1;
  }
}

extern "C" void kernel_launch(void* const* d_in, const int* in_sizes, int n_in,
                              void* d_out, int out_size, void* d_ws, size_t ws_size,
                              hipStream_t stream) {
  const float* x  = (const float*)d_in[0];
  const float* w1 = (const float*)d_in[1];
  const float* b1 = (const float*)d_in[2];
  const float* w2 = (const float*)d_in[3];
  const float* b2 = (const float*)d_in[4];
  const float* pw = (const float*)d_in[5];
  char* ws = (char*)d_ws;
  _Float16* u   = (_Float16*)ws;                                   // 2 MiB
  _Float16* v   = (_Float16*)(ws + (2u << 20));                    // 2 MiB
  _Float16* w2t = (_Float16*)(ws + (4u << 20));                    // 256 KiB
  float*    pwt = (float*)(ws + (5u << 20));                       // 4 MiB
  unsigned short* yt = (unsigned short*)(ws + (9u << 20));         // 64 MiB f16
  float* out = (float*)d_out;

  k_uv<<<dim3(256), dim3(256), 0, stream>>>(x, w1, b1, u, v);
  k_w2t<<<dim3(256), dim3(256), 0, stream>>>(w2, w2t);
  k_pwt<<<dim3(256), dim3(256), 0, stream>>>(pw, pwt);
  k_gemm<<<dim3(512), dim3(256), 0, stream>>>(u, v, w2t, b2, yt);
  k_sortpool<<<dim3(4096), dim3(64), 0, stream>>>(yt, pwt, out);
}